// Round 3
// baseline (476.892 us; speedup 1.0000x reference)
//
#include <hip/hip_runtime.h>
#include <hip/hip_cooperative_groups.h>
#include <math.h>

namespace cg = cooperative_groups;

#define BB 16
#define TT 2048
#define DD 1024
#define THRESH 0.95f
#define RPB 8                      // output rows per gather chunk
#define NCHUNK (BB * (TT / RPB))   // 4096 chunks
#define NBLK 1024                  // cooperative grid: 4 blocks/CU x 256 CU
#define GBLK (NBLK - BB)           // 1008 gather blocks
#define DONEBIT 0x40000000u

typedef float nt4 __attribute__((ext_vector_type(4)));

__device__ __forceinline__ void nt_store4(const float4& v, float4* p) {
    nt4 x = {v.x, v.y, v.z, v.w};
    __builtin_nontemporal_store(x, (nt4*)p);
}

// Serial integrate-and-fire over one 64-step group held in RREG (one alpha
// per lane). Chain is bit-identical to the reference. Lane j captures step
// j's cur value; lane GIDX accumulates the group's fire mask.
#define SCAN_GROUP(RREG, GIDX)                                                \
    {                                                                         \
        float cv = 0.f, pv = 0.f;                                             \
        _Pragma("unroll 16")                                                  \
        for (int j = 0; j < 64; ++j) {                                        \
            float a = __int_as_float(                                         \
                __builtin_amdgcn_readlane(__float_as_int(RREG), j));          \
            float pre  = integ + a;              /* chain: v_add */           \
            bool  fire = pre > THRESH;           /* chain: v_cmp */           \
            float c    = fire ? dist : a;                                     \
            integ      = fire ? pre - 1.f : pre; /* chain: v_cndmask */       \
            dist       = 1.f - integ;                                         \
            bool sel   = (lane == j);                                         \
            cv = sel ? c   : cv;                                              \
            pv = sel ? pre : pv;                                              \
        }                                                                     \
        cp[(GIDX) * 64 + lane] = cv;                                          \
        unsigned long long bm = __ballot(pv > THRESH);                        \
        gmask = (lane == (GIDX)) ? bm : gmask;                                \
    }

// =====================================================================
// Fused cooperative kernel: proj -> grid.sync -> { scan || gather }
// Scan blocks (0..15) publish fires_so_far per 512-step pass via
// release-store; gather blocks acquire-spin until their chunk's fire
// times exist. Co-residency guaranteed by cooperative launch -> no
// dispatch-order assumption (G16-safe).
// =====================================================================
__global__ __launch_bounds__(256, 4) void fused_kernel(
    const float* __restrict__ hs, const float* __restrict__ hs_mask,
    const float* __restrict__ w, const float* __restrict__ bias,
    float* __restrict__ out, float* __restrict__ out_mask,
    float* __restrict__ alphas, float* __restrict__ cur,
    int* __restrict__ fire_times, unsigned* __restrict__ progress)
{
    __shared__ int s_nf;

    // ---------------- Phase 1: projection (all blocks, 32 rows each) ----
    {
        int lane = threadIdx.x & 63;
        const float4* wp = (const float4*)w;
        float4 w0 = wp[lane], w1 = wp[lane + 64],
               w2 = wp[lane + 128], w3 = wp[lane + 192];
        int row0 = blockIdx.x * (BB * TT / NBLK) + (threadIdx.x >> 6);
#pragma unroll
        for (int it = 0; it < (BB * TT / NBLK); it += 4) {
            int row = row0 + it;
            const float4* hp = (const float4*)(hs + (size_t)row * DD);
            float4 h0 = hp[lane], h1 = hp[lane + 64],
                   h2 = hp[lane + 128], h3 = hp[lane + 192];
            float sum = h0.x * w0.x + h0.y * w0.y + h0.z * w0.z + h0.w * w0.w
                      + h1.x * w1.x + h1.y * w1.y + h1.z * w1.z + h1.w * w1.w
                      + h2.x * w2.x + h2.y * w2.y + h2.z * w2.z + h2.w * w2.w
                      + h3.x * w3.x + h3.y * w3.y + h3.z * w3.z + h3.w * w3.w;
#pragma unroll
            for (int off = 32; off; off >>= 1) sum += __shfl_down(sum, off, 64);
            if (lane == 0) {
                float x  = sum + bias[0];
                float al = 1.f / (1.f + expf(-x));
                alphas[row] = al * hs_mask[row];
            }
        }
        if (blockIdx.x == 0 && threadIdx.x < BB) progress[threadIdx.x] = 0u;
    }

    cg::this_grid().sync();

    // ---------------- Phase 2a: scan blocks (0..15) --------------------
    if (blockIdx.x < BB) {
        if (threadIdx.x >= 64) return;       // one wave per scan block
        int b    = blockIdx.x;
        int lane = threadIdx.x;
        const float* ap = alphas + (size_t)b * TT;
        float*       cp = cur    + (size_t)b * TT;
        int*         fp = fire_times + (size_t)b * TT;

        unsigned long long gmask = 0ull;     // lane g holds mask of time-group g
        float integ = 0.f, dist = 1.f;
        double dsum = 0.0;
        int base_fires = 0;

        for (int outer = 0; outer < 4; ++outer) {
            int base = outer * 512 + lane;
            float r0 = ap[base +   0];
            float r1 = ap[base +  64];
            float r2 = ap[base + 128];
            float r3 = ap[base + 192];
            float r4 = ap[base + 256];
            float r5 = ap[base + 320];
            float r6 = ap[base + 384];
            float r7 = ap[base + 448];
            dsum += (double)r0 + (double)r1 + (double)r2 + (double)r3
                  + (double)r4 + (double)r5 + (double)r6 + (double)r7;
            int gb = outer * 8;
            SCAN_GROUP(r0, gb + 0)
            SCAN_GROUP(r1, gb + 1)
            SCAN_GROUP(r2, gb + 2)
            SCAN_GROUP(r3, gb + 3)
            SCAN_GROUP(r4, gb + 4)
            SCAN_GROUP(r5, gb + 5)
            SCAN_GROUP(r6, gb + 6)
            SCAN_GROUP(r7, gb + 7)

            // Expand THIS pass's fires -> fire_times (lanes gb..gb+7 hold them)
            bool inpass = (lane >= gb) && (lane < gb + 8);
            unsigned long long mym = inpass ? gmask : 0ull;
            int cnt  = __popcll(mym);
            int pref = cnt;
#pragma unroll
            for (int off = 1; off < 64; off <<= 1) {
                int y = __shfl_up(pref, off, 64);
                if (lane >= off) pref += y;
            }
            int pass_total = __shfl(pref, 63, 64);
            int pos = base_fires + pref - cnt;
            unsigned long long m = mym;
            int baset = lane * 64;
            while (m) {
                int j = __ffsll(m) - 1;
                fp[pos++] = baset + j;
                m &= m - 1;
            }
            base_fires += pass_total;

            // Publish progress (release: cur/fire_times stores drained first)
            __threadfence();
            if (lane == 0) {
                unsigned val = (outer == 3) ? ((unsigned)base_fires | DONEBIT)
                                            : (unsigned)base_fires;
                __hip_atomic_store(&progress[b], val, __ATOMIC_RELEASE,
                                   __HIP_MEMORY_SCOPE_AGENT);
            }
        }

        // len + out_mask (order-insensitive sum; round tolerance huge)
#pragma unroll
        for (int off = 32; off; off >>= 1) dsum += __shfl_down(dsum, off, 64);
        int len = __double2int_rn(dsum);
        len = __shfl(len, 0, 64);
        float* mp = out_mask + (size_t)b * TT;
#pragma unroll
        for (int j = 0; j < TT / 64; ++j)
            mp[j * 64 + lane] = ((j * 64 + lane) < len) ? 1.f : 0.f;
        return;
    }

    // ---------------- Phase 2b: gather blocks (16..1023) ----------------
    int gk = blockIdx.x - BB;
    int ti = threadIdx.x;
    for (int c = gk; c < NCHUNK; c += GBLK) {
        int b  = c & (BB - 1);
        int r0 = (c >> 4) * RPB;

        if (threadIdx.x == 0) {
            int need = r0 + RPB;
            unsigned v;
            for (;;) {
                v = __hip_atomic_load(&progress[b], __ATOMIC_ACQUIRE,
                                      __HIP_MEMORY_SCOPE_AGENT);
                if (v & DONEBIT) { v &= ~DONEBIT; break; }
                if ((int)v >= need) break;   // all our rows' fires published
                __builtin_amdgcn_s_sleep(2);
            }
            s_nf = (int)v;                   // == nf when DONE; lower bound else
        }
        __syncthreads();
        int nf = s_nf;
        __syncthreads();                     // protect s_nf before next chunk

        float4* ob = (float4*)(out + ((size_t)b * TT + r0) * DD);

        if (r0 >= nf) {                      // only reachable with DONE
            float4 z = {0.f, 0.f, 0.f, 0.f};
#pragma unroll
            for (int i = 0; i < RPB; ++i)
                nt_store4(z, &ob[i * 256 + ti]);
            continue;
        }

        const int*    ft  = fire_times + (size_t)b * TT;
        const float*  al  = alphas     + (size_t)b * TT;
        const float*  cu  = cur        + (size_t)b * TT;
        const float4* hsb = (const float4*)(hs + (size_t)b * TT * DD);

        int    t;
        float4 hprev = {0.f, 0.f, 0.f, 0.f};
        float  wprev = 0.f;
        bool   have_prev;
        if (r0 == 0) {
            t = 0;
            have_prev = false;
        } else {
            int tp = ft[r0 - 1];
            t = tp + 1;
            hprev = hsb[(size_t)tp * 256 + ti];
            wprev = al[tp] - cu[tp];
            have_prev = true;
        }

#pragma unroll
        for (int i = 0; i < RPB; ++i) {
            int r = r0 + i;
            float4 a = {0.f, 0.f, 0.f, 0.f};
            if (r < nf) {
                if (have_prev) {             // boundary term FIRST (reference order)
                    a.x = wprev * hprev.x; a.y = wprev * hprev.y;
                    a.z = wprev * hprev.z; a.w = wprev * hprev.w;
                }
                int te = ft[r];
                for (;;) {
                    float4 h  = hsb[(size_t)t * 256 + ti];
                    float  cw = cu[t];
                    a.x += cw * h.x; a.y += cw * h.y;
                    a.z += cw * h.z; a.w += cw * h.w;
                    if (t == te) {
                        wprev = al[t] - cw;
                        hprev = h;
                        ++t;
                        break;
                    }
                    ++t;
                }
                have_prev = true;
            }
            nt_store4(a, &ob[i * 256 + ti]);
        }
    }
}

// =====================================================================
// Fallback path (proven 3-kernel pipeline) — used if cooperative launch
// is rejected (e.g. by graph capture).
// =====================================================================
__global__ __launch_bounds__(256) void proj_kernel(
    const float* __restrict__ hs, const float* __restrict__ hs_mask,
    const float* __restrict__ w, const float* __restrict__ bias,
    float* __restrict__ alphas)
{
    int row  = blockIdx.x * 4 + (threadIdx.x >> 6);
    int lane = threadIdx.x & 63;
    const float4* hp = (const float4*)(hs + (size_t)row * DD);
    const float4* wp = (const float4*)w;
    float sum = 0.f;
#pragma unroll
    for (int j = 0; j < 4; ++j) {
        float4 h4 = hp[lane + 64 * j];
        float4 w4 = wp[lane + 64 * j];
        sum += h4.x * w4.x + h4.y * w4.y + h4.z * w4.z + h4.w * w4.w;
    }
#pragma unroll
    for (int off = 32; off; off >>= 1) sum += __shfl_down(sum, off, 64);
    if (lane == 0) {
        float x  = sum + bias[0];
        float al = 1.f / (1.f + expf(-x));
        alphas[row] = al * hs_mask[row];
    }
}

__global__ __launch_bounds__(64) void scan_kernel(
    const float* __restrict__ alphas, float* __restrict__ cur,
    int* __restrict__ fire_times, int* __restrict__ n_fires,
    float* __restrict__ out_mask)
{
    int b    = blockIdx.x;
    int lane = threadIdx.x;
    const float* ap = alphas + (size_t)b * TT;
    float*       cp = cur    + (size_t)b * TT;

    unsigned long long gmask = 0ull;
    float integ = 0.f, dist = 1.f;
    double dsum = 0.0;

    for (int outer = 0; outer < 4; ++outer) {
        int base = outer * 512 + lane;
        float r0 = ap[base +   0];
        float r1 = ap[base +  64];
        float r2 = ap[base + 128];
        float r3 = ap[base + 192];
        float r4 = ap[base + 256];
        float r5 = ap[base + 320];
        float r6 = ap[base + 384];
        float r7 = ap[base + 448];
        dsum += (double)r0 + (double)r1 + (double)r2 + (double)r3
              + (double)r4 + (double)r5 + (double)r6 + (double)r7;
        int gb = outer * 8;
        SCAN_GROUP(r0, gb + 0)
        SCAN_GROUP(r1, gb + 1)
        SCAN_GROUP(r2, gb + 2)
        SCAN_GROUP(r3, gb + 3)
        SCAN_GROUP(r4, gb + 4)
        SCAN_GROUP(r5, gb + 5)
        SCAN_GROUP(r6, gb + 6)
        SCAN_GROUP(r7, gb + 7)
    }

#pragma unroll
    for (int off = 32; off; off >>= 1) dsum += __shfl_down(dsum, off, 64);
    int len = __double2int_rn(dsum);
    len = __shfl(len, 0, 64);

    float* mp = out_mask + (size_t)b * TT;
#pragma unroll
    for (int j = 0; j < TT / 64; ++j)
        mp[j * 64 + lane] = ((j * 64 + lane) < len) ? 1.f : 0.f;

    int cnt  = __popcll(gmask);
    int pref = cnt;
#pragma unroll
    for (int off = 1; off < 64; off <<= 1) {
        int y = __shfl_up(pref, off, 64);
        if (lane >= off) pref += y;
    }
    int pos = pref - cnt;
    unsigned long long m = gmask;
    int baset = lane * 64;
    int* fp = fire_times + (size_t)b * TT;
    while (m) {
        int j = __ffsll(m) - 1;
        fp[pos++] = baset + j;
        m &= m - 1;
    }
    if (lane == 63) n_fires[b] = pref;
}

__global__ __launch_bounds__(256) void gather_kernel(
    const float* __restrict__ hs, const float* __restrict__ alphas,
    const float* __restrict__ cur, const int* __restrict__ fire_times,
    const int* __restrict__ n_fires, float* __restrict__ out)
{
    int chunk = blockIdx.x;
    int b  = chunk >> 8;
    int r0 = (chunk & 255) * RPB;
    int ti = threadIdx.x;
    int nf = n_fires[b];

    float4* ob = (float4*)(out + ((size_t)b * TT + r0) * DD);

    if (r0 >= nf) {
        float4 z = {0.f, 0.f, 0.f, 0.f};
#pragma unroll
        for (int i = 0; i < RPB; ++i)
            nt_store4(z, &ob[i * 256 + ti]);
        return;
    }

    const int*    ft  = fire_times + (size_t)b * TT;
    const float*  al  = alphas     + (size_t)b * TT;
    const float*  cu  = cur        + (size_t)b * TT;
    const float4* hsb = (const float4*)(hs + (size_t)b * TT * DD);

    int    t;
    float4 hprev = {0.f, 0.f, 0.f, 0.f};
    float  wprev = 0.f;
    bool   have_prev;
    if (r0 == 0) {
        t = 0;
        have_prev = false;
    } else {
        int tp = ft[r0 - 1];
        t = tp + 1;
        hprev = hsb[(size_t)tp * 256 + ti];
        wprev = al[tp] - cu[tp];
        have_prev = true;
    }

#pragma unroll
    for (int i = 0; i < RPB; ++i) {
        int r = r0 + i;
        float4 a = {0.f, 0.f, 0.f, 0.f};
        if (r < nf) {
            if (have_prev) {
                a.x = wprev * hprev.x; a.y = wprev * hprev.y;
                a.z = wprev * hprev.z; a.w = wprev * hprev.w;
            }
            int te = ft[r];
            for (;;) {
                float4 h  = hsb[(size_t)t * 256 + ti];
                float  cw = cu[t];
                a.x += cw * h.x; a.y += cw * h.y;
                a.z += cw * h.z; a.w += cw * h.w;
                if (t == te) {
                    wprev = al[t] - cw;
                    hprev = h;
                    ++t;
                    break;
                }
                ++t;
            }
            have_prev = true;
        }
        nt_store4(a, &ob[i * 256 + ti]);
    }
}

extern "C" void kernel_launch(void* const* d_in, const int* in_sizes, int n_in,
                              void* d_out, int out_size, void* d_ws, size_t ws_size,
                              hipStream_t stream) {
    const float* hs      = (const float*)d_in[0];   // [B,T,D]
    const float* hs_mask = (const float*)d_in[1];   // [B,1,T]
    const float* w       = (const float*)d_in[2];   // [D]
    const float* bias    = (const float*)d_in[3];   // scalar

    float* out      = (float*)d_out;                       // [B,T,D]
    float* out_mask = out + (size_t)BB * TT * DD;          // [B,1,T] as 0/1 floats

    float*    alphas     = (float*)d_ws;                   // B*T floats
    float*    cur        = alphas + BB * TT;               // B*T floats
    int*      fire_times = (int*)(cur + BB * TT);          // B*T ints
    int*      n_fires    = fire_times + BB * TT;           // B ints
    unsigned* progress   = (unsigned*)(n_fires + BB);      // B unsigned

    void* args[] = {(void*)&hs, (void*)&hs_mask, (void*)&w, (void*)&bias,
                    (void*)&out, (void*)&out_mask, (void*)&alphas, (void*)&cur,
                    (void*)&fire_times, (void*)&progress};
    hipError_t e = hipLaunchCooperativeKernel((const void*)fused_kernel,
                                              dim3(NBLK), dim3(256),
                                              args, 0, stream);
    if (e != hipSuccess) {
        // Fallback: proven 3-kernel pipeline (stream-ordered, no co-residency needs)
        proj_kernel<<<BB * TT / 4, 256, 0, stream>>>(hs, hs_mask, w, bias, alphas);
        scan_kernel<<<BB, 64, 0, stream>>>(alphas, cur, fire_times, n_fires,
                                           out_mask);
        gather_kernel<<<BB * (TT / RPB), 256, 0, stream>>>(hs, alphas, cur,
                                                           fire_times, n_fires, out);
    }
}

// Round 4
// 304.849 us; speedup vs baseline: 1.5644x; 1.5644x over previous
//
#include <hip/hip_runtime.h>
#include <math.h>

#define BB 16
#define TT 2048
#define DD 1024
#define THRESH 0.95f
#define RPB 8   // output rows per gather block (TT/RPB = 256 chunks per batch)

typedef float nt4 __attribute__((ext_vector_type(4)));

__device__ __forceinline__ void nt_store4(const float4& v, float4* p) {
    nt4 x = {v.x, v.y, v.z, v.w};
    __builtin_nontemporal_store(x, (nt4*)p);
}

// ---------------- Kernel 1: projection + sigmoid + mask ----------------
__global__ __launch_bounds__(256) void proj_kernel(
    const float* __restrict__ hs, const float* __restrict__ hs_mask,
    const float* __restrict__ w, const float* __restrict__ bias,
    float* __restrict__ alphas)
{
    int row  = blockIdx.x * 4 + (threadIdx.x >> 6);   // b*T + t
    int lane = threadIdx.x & 63;
    const float4* hp = (const float4*)(hs + (size_t)row * DD);
    const float4* wp = (const float4*)w;
    float sum = 0.f;
#pragma unroll
    for (int j = 0; j < 4; ++j) {
        float4 h4 = hp[lane + 64 * j];
        float4 w4 = wp[lane + 64 * j];
        sum += h4.x * w4.x + h4.y * w4.y + h4.z * w4.z + h4.w * w4.w;
    }
#pragma unroll
    for (int off = 32; off; off >>= 1) sum += __shfl_down(sum, off, 64);
    if (lane == 0) {
        float x  = sum + bias[0];
        float al = 1.f / (1.f + expf(-x));   // expf: fire decisions are rounding-sensitive
        alphas[row] = al * hs_mask[row];
    }
}

// ---------------- Kernel 2: integrate-and-fire scan (serial-exact) ----------------
// One wave per batch. Serial fp32 chain bit-identical to the reference.
// NEW vs R2: (a) cur[t] is stored SIGN-TAGGED: sign bit = fire flag
// (cur is provably >= 0: alpha in [0,1), dist in (0.05,1.05]), so gather
// needs no fire_times sequencing in its hot loop; (b) fire_times[nf..TT)
// is PADDED with the last fire time so gather can load its chunk's end
// time unconditionally (known trip count -> pipelineable stream).

#define SCAN_GROUP(RREG, GIDX)                                                \
    {                                                                         \
        float cv = 0.f, pv = 0.f;                                             \
        _Pragma("unroll 16")                                                  \
        for (int j = 0; j < 64; ++j) {                                        \
            float a = __int_as_float(                                         \
                __builtin_amdgcn_readlane(__float_as_int(RREG), j));          \
            float pre  = integ + a;              /* chain: v_add */           \
            bool  fire = pre > THRESH;           /* chain: v_cmp */           \
            float c    = fire ? dist : a;                                     \
            integ      = fire ? pre - 1.f : pre; /* chain: v_cndmask */       \
            dist       = 1.f - integ;                                         \
            bool sel   = (lane == j);                                         \
            cv = sel ? c   : cv;                                              \
            pv = sel ? pre : pv;                                              \
        }                                                                     \
        bool myfire = pv > THRESH;                                            \
        cp[(GIDX) * 64 + lane] = myfire ? -cv : cv;   /* sign-tagged */       \
        unsigned long long bm = __ballot(myfire);                             \
        gmask = (lane == (GIDX)) ? bm : gmask;                                \
    }

__global__ __launch_bounds__(64) void scan_kernel(
    const float* __restrict__ alphas, float* __restrict__ cur,
    int* __restrict__ fire_times, float* __restrict__ out_mask)
{
    int b    = blockIdx.x;
    int lane = threadIdx.x;                  // 0..63, one wave
    const float* ap = alphas + (size_t)b * TT;
    float*       cp = cur    + (size_t)b * TT;

    unsigned long long gmask = 0ull;         // lane g: fire mask of steps [g*64,(g+1)*64)
    float integ = 0.f, dist = 1.f;
    double dsum = 0.0;

    for (int outer = 0; outer < 4; ++outer) {
        int base = outer * 512 + lane;
        float r0 = ap[base +   0];
        float r1 = ap[base +  64];
        float r2 = ap[base + 128];
        float r3 = ap[base + 192];
        float r4 = ap[base + 256];
        float r5 = ap[base + 320];
        float r6 = ap[base + 384];
        float r7 = ap[base + 448];
        dsum += (double)r0 + (double)r1 + (double)r2 + (double)r3
              + (double)r4 + (double)r5 + (double)r6 + (double)r7;
        int gb = outer * 8;
        SCAN_GROUP(r0, gb + 0)
        SCAN_GROUP(r1, gb + 1)
        SCAN_GROUP(r2, gb + 2)
        SCAN_GROUP(r3, gb + 3)
        SCAN_GROUP(r4, gb + 4)
        SCAN_GROUP(r5, gb + 5)
        SCAN_GROUP(r6, gb + 6)
        SCAN_GROUP(r7, gb + 7)
    }

    // len + out_mask (order-insensitive sum; round tolerance huge)
#pragma unroll
    for (int off = 32; off; off >>= 1) dsum += __shfl_down(dsum, off, 64);
    int len = __double2int_rn(dsum);
    len = __shfl(len, 0, 64);
    float* mp = out_mask + (size_t)b * TT;
#pragma unroll
    for (int j = 0; j < TT / 64; ++j)
        mp[j * 64 + lane] = ((j * 64 + lane) < len) ? 1.f : 0.f;

    // Expand fire masks -> fire_times (order-preserving prefix over 32 groups)
    int cnt  = __popcll(gmask);
    int pref = cnt;
#pragma unroll
    for (int off = 1; off < 64; off <<= 1) {
        int y = __shfl_up(pref, off, 64);
        if (lane >= off) pref += y;
    }
    int pos = pref - cnt;
    unsigned long long m = gmask;
    int baset = lane * 64;
    int* fp = fire_times + (size_t)b * TT;
    while (m) {
        int j = __ffsll(m) - 1;
        fp[pos++] = baset + j;
        m &= m - 1;
    }

    // Pad fire_times[nf..TT) with the last fire time (0 if none) so gather
    // can load ft[r0+RPB-1] / ft[r0-1] unconditionally over poisoned ws.
    int nf = __shfl(pref, 63, 64);
    int lastf = 0;
    if (nf > 0) lastf = fp[nf - 1];          // uniform-address broadcast load
    for (int r = nf + lane; r < TT; r += 64) fp[r] = lastf;
}

// ---------------- Kernel 3: counted-stream gather ----------------
// One block owns RPB consecutive output rows. The block's full frame range
// [t0, t1] is known UPFRONT (t1 = ft[r0+RPB-1], padded), so the hot loop is
// a counted stream: load frame t, fire flag = sign bit of cur[t] (wave-
// uniform -> no divergence), on fire store the completed row to the next
// sequential row pointer and reseed the accumulator with the boundary term.
// No data-dependent exit -> compiler can issue t+1 loads ahead of the branch.
__global__ __launch_bounds__(256) void gather_kernel(
    const float* __restrict__ hs, const float* __restrict__ alphas,
    const float* __restrict__ cur, const int* __restrict__ fire_times,
    float* __restrict__ out)
{
    int chunk = blockIdx.x;          // b * (TT/RPB) + c
    int b  = chunk >> 8;             // TT/RPB = 256
    int r0 = (chunk & 255) * RPB;
    int ti = threadIdx.x;            // 0..255, covers D via float4

    const int*    ft  = fire_times + (size_t)b * TT;
    const float*  al  = alphas     + (size_t)b * TT;
    const float*  cu  = cur        + (size_t)b * TT;
    const float4* hsb = (const float4*)(hs + (size_t)b * TT * DD);
    float4*       ob  = (float4*)(out + ((size_t)b * TT + r0) * DD);

    int t1 = ft[r0 + RPB - 1];       // padded -> always valid
    int t;
    float4 acc = {0.f, 0.f, 0.f, 0.f};
    if (r0 == 0) {
        t = 0;
    } else {
        int   tp = ft[r0 - 1];       // boundary frame (last fire of prev row)
        float cr = cu[tp];
        float wb = al[tp] - fabsf(cr);
        float4 h = hsb[(size_t)tp * 256 + ti];
        acc.x = wb * h.x; acc.y = wb * h.y;   // boundary term FIRST (reference order)
        acc.z = wb * h.z; acc.w = wb * h.w;
        t = tp + 1;
    }

    int emitted = 0;
#pragma unroll 2
    for (; t <= t1; ++t) {
        float  cr = cu[t];           // broadcast scalar; sign bit = fire flag
        float4 h  = hsb[(size_t)t * 256 + ti];
        float  cw = fabsf(cr);
        acc.x += cw * h.x; acc.y += cw * h.y;
        acc.z += cw * h.z; acc.w += cw * h.w;
        if (cr < 0.f) {              // fire: close this row (wave-uniform branch)
            nt_store4(acc, &ob[(size_t)emitted * 256 + ti]);
            float wb = al[t] - cw;   // reseed with boundary term for next row
            acc.x = wb * h.x; acc.y = wb * h.y;
            acc.z = wb * h.z; acc.w = wb * h.w;
            ++emitted;
        }
    }

    // Rows past the last fire stay zero.
    float4 z = {0.f, 0.f, 0.f, 0.f};
    for (int i = emitted; i < RPB; ++i)
        nt_store4(z, &ob[(size_t)i * 256 + ti]);
}

extern "C" void kernel_launch(void* const* d_in, const int* in_sizes, int n_in,
                              void* d_out, int out_size, void* d_ws, size_t ws_size,
                              hipStream_t stream) {
    const float* hs      = (const float*)d_in[0];   // [B,T,D]
    const float* hs_mask = (const float*)d_in[1];   // [B,1,T]
    const float* w       = (const float*)d_in[2];   // [D]
    const float* bias    = (const float*)d_in[3];   // scalar

    float* out      = (float*)d_out;                       // [B,T,D]
    float* out_mask = out + (size_t)BB * TT * DD;          // [B,1,T] as 0/1 floats

    float* alphas     = (float*)d_ws;                      // B*T floats
    float* cur        = alphas + BB * TT;                  // B*T floats (sign-tagged)
    int*   fire_times = (int*)(cur + BB * TT);             // B*T ints (padded)

    proj_kernel<<<BB * TT / 4, 256, 0, stream>>>(hs, hs_mask, w, bias, alphas);
    scan_kernel<<<BB, 64, 0, stream>>>(alphas, cur, fire_times, out_mask);
    gather_kernel<<<BB * (TT / RPB), 256, 0, stream>>>(hs, alphas, cur,
                                                       fire_times, out);
}